// Round 8
// baseline (654.803 us; speedup 1.0000x reference)
//
#include <hip/hip_runtime.h>
#include <hip/hip_fp16.h>
#include <math.h>

#define DIM 64
#define HEADS 8
#define HIDDEN 256

struct h2x2 { __half2 a, b; };   // 8B packed fp16 quad
struct h2x4 { __half2 a, b, c, d; };  // 16B packed fp16 octet

// readlane: broadcast lane `srcLane`'s value to all lanes (srcLane must be wave-uniform)
__device__ __forceinline__ float lane_bcast(float v, int srcLane) {
  return __int_as_float(__builtin_amdgcn_readlane(__float_as_int(v), srcLane));
}

// ---------------- prep: fold linear chains into combined weights ----------------
__global__ void prep_kernel(
    const float* __restrict__ w_in, const float* __restrict__ b_in,
    const float* __restrict__ w_edge, const float* __restrict__ b_edge,
    const float* __restrict__ w_att_u, const float* __restrict__ b_att_u,
    const float* __restrict__ w_att_v,
    const float* __restrict__ w_att_e, const float* __restrict__ b_att_e,
    float* __restrict__ Waug, float* __restrict__ baug,
    float* __restrict__ wcc, float* __restrict__ bcc)
{
  int t = threadIdx.x; // 256 threads
  if (t < 64) {
    for (int j = 0; j < 64; ++j) Waug[t*80 + j] = w_in[t*64 + j];
    for (int hh = 0; hh < 8; ++hh) {
      float a = 0.f, b = 0.f;
      for (int j = 0; j < 64; ++j) {
        float w = w_in[t*64 + j];
        a += w * w_att_u[j*8 + hh];
        b += w * w_att_v[j*8 + hh];
      }
      Waug[t*80 + 64 + hh] = a;
      Waug[t*80 + 72 + hh] = b;
    }
  } else if (t < 128) {
    int j = t - 64;
    baug[j] = b_in[j];
  } else if (t < 136) {
    int hh = t - 128;
    float a = b_att_u[hh];
    for (int k = 0; k < 64; ++k) a += b_in[k] * w_att_u[k*8 + hh];
    baug[64 + hh] = a;
  } else if (t < 144) {
    int hh = t - 136;
    float a = 0.f;
    for (int k = 0; k < 64; ++k) a += b_in[k] * w_att_v[k*8 + hh];
    baug[72 + hh] = a;
  } else if (t < 160) {
    int c = (t - 144) >> 3, hh = (t - 144) & 7;
    float a = 0.f;
    for (int j = 0; j < 64; ++j) a += w_edge[c*64 + j] * w_att_e[j*8 + hh];
    wcc[c*8 + hh] = a;
  } else if (t < 168) {
    int hh = t - 160;
    float a = b_att_e[hh];
    for (int j = 0; j < 64; ++j) a += b_edge[j] * w_att_e[j*8 + hh];
    bcc[hh] = a;
  }
}

// ---------------- node GEMM: [N,64] @ [64,80] -> h(fp16), su(fp16), sv(fp32) ----------------
// Wave per 8 nodes; lane owns output column; x broadcast via v_readlane.
__global__ __launch_bounds__(256) void node_gemm_kernel(
    const float* __restrict__ x,
    const float* __restrict__ Waug, const float* __restrict__ baug,
    __half* __restrict__ hbuf16, __half* __restrict__ subuf16,
    float* __restrict__ svbuf, int n_nodes)
{
  const int wid = threadIdx.x >> 6;
  const int lane = threadIdx.x & 63;
  const long nbase = (long)blockIdx.x * 32 + wid * 8;

  float xr[8];
  #pragma unroll
  for (int m = 0; m < 8; ++m) {
    long n = nbase + m; if (n >= n_nodes) n = n_nodes - 1;
    xr[m] = x[n*DIM + lane];          // coalesced 256B row read
  }
  const float bmain = baug[lane];
  const float bext  = (lane < 16) ? baug[64 + lane] : 0.f;
  float acc[8], acc2[8];
  #pragma unroll
  for (int m = 0; m < 8; ++m) { acc[m] = bmain; acc2[m] = 0.f; }

  #pragma unroll 16
  for (int k = 0; k < 64; ++k) {
    float wmain = Waug[k*80 + lane];                       // coalesced
    float wext  = (lane < 16) ? Waug[k*80 + 64 + lane] : 0.f;
    #pragma unroll
    for (int m = 0; m < 8; ++m) {
      float xk = lane_bcast(xr[m], k);
      acc[m]  += xk * wmain;
      acc2[m] += xk * wext;
    }
  }
  #pragma unroll
  for (int m = 0; m < 8; ++m) {
    long n = nbase + m;
    if (n >= n_nodes) continue;
    hbuf16[n*DIM + lane] = __float2half(acc[m]);           // 128B contiguous/row
    if (lane < 8)       subuf16[n*8 + lane]   = __float2half(acc2[m] + bext);
    else if (lane < 16) svbuf[n*8 + lane - 8] = acc2[m] + bext;
  }
}

// ---------------- CSR build ----------------
__global__ void hist_kernel(const int* __restrict__ dst, int* __restrict__ deg, int n_edges) {
  int i = blockIdx.x * blockDim.x + threadIdx.x;
  if (i < n_edges) atomicAdd(&deg[dst[i]], 1);
}

__global__ void alloc_kernel(const int* __restrict__ deg, int* __restrict__ off,
                             int* __restrict__ counter, int n_nodes) {
  int i = blockIdx.x * blockDim.x + threadIdx.x;
  int lane = threadIdx.x & 63;
  int d = (i < n_nodes) ? deg[i] : 0;
  int pre = d;
  #pragma unroll
  for (int s = 1; s < 64; s <<= 1) {
    int v = __shfl_up(pre, s, 64);
    if (lane >= s) pre += v;
  }
  int tot = __shfl(pre, 63, 64);
  int base = 0;
  if (lane == 0) base = atomicAdd(counter, tot);
  base = __shfl(base, 0, 64);
  if (i < n_nodes) off[i] = base + pre - d;
}

// scatter: write packed 16B record {src, ef.x, ef.y, 0} per CSR slot — attn
// then does ONE coalesced 16B read per edge instead of csr+src+edge_feat
// random line fetches.
__global__ void scatter_kernel(const int* __restrict__ dst, const int* __restrict__ src,
                               const float* __restrict__ edge_feat,
                               const int* __restrict__ off,
                               int* __restrict__ pos, int4* __restrict__ recs, int n_edges) {
  int i = blockIdx.x * blockDim.x + threadIdx.x;
  if (i < n_edges) {
    int d = dst[i];
    int p = atomicAdd(&pos[d], 1);
    float2 ef = *(const float2*)(edge_feat + (long)i*2);   // coalesced by i
    int4 rec;
    rec.x = src[i];                                        // coalesced by i
    rec.y = __float_as_int(ef.x);
    rec.z = __float_as_int(ef.y);
    rec.w = 0;
    recs[off[d] + p] = rec;
  }
}

// ---------------- attention gather: 16-lane group per dst node ----------------
// fp16 h/su gathers (half traffic), packed records, swizzled pbuf.
__global__ __launch_bounds__(256) void attn_kernel(
    const int4* __restrict__ recs,
    const int* __restrict__ off, const int* __restrict__ deg,
    const __half* __restrict__ hbuf16, const __half* __restrict__ subuf16,
    const float* __restrict__ svbuf,
    const float* __restrict__ wcc, const float* __restrict__ bcc,
    float* __restrict__ agg, int n_nodes)
{
  __shared__ float pbuf[4][16][4][8];   // [wid][e2][g^swz][head] : 8 KB
  __shared__ int   sbuf[4][16][4];      // 1 KB
  const int wid = threadIdx.x >> 6;
  const int lane = threadIdx.x & 63;
  const int g = lane >> 4, sub = lane & 15;
  const long n = (long)blockIdx.x * 16 + wid * 4 + g;
  const bool valid = (n < n_nodes);
  const long nc = valid ? n : (long)(n_nodes - 1);
  const int ebase = off[nc];
  const int d = valid ? deg[nc] : 0;
  const int hb = (sub & 1) * 4;   // head base for this lane's 4 dims

  float svn[8], c0v[8], c1v[8], cbv[8];
  {
    const float4* svp = (const float4*)(svbuf + nc*8);
    float4 s0 = svp[0], s1 = svp[1];
    svn[0]=s0.x; svn[1]=s0.y; svn[2]=s0.z; svn[3]=s0.w;
    svn[4]=s1.x; svn[5]=s1.y; svn[6]=s1.z; svn[7]=s1.w;
    #pragma unroll
    for (int hh = 0; hh < 8; ++hh) {
      c0v[hh] = wcc[hh]; c1v[hh] = wcc[8+hh]; cbv[hh] = bcc[hh];
    }
  }
  float m8[8], den8[8];
  #pragma unroll
  for (int hh = 0; hh < 8; ++hh) { m8[hh] = -INFINITY; den8[hh] = 0.f; }
  float4 msg = make_float4(0.f, 0.f, 0.f, 0.f);

  for (int c0 = 0; c0 < d; c0 += 16) {
    const int cnt = min(16, d - c0);
    float sc[8];
    int sid = 0;
    if (sub < cnt) {
      int4 rec = recs[ebase + c0 + sub];               // ONE coalesced 16B read
      sid = rec.x;
      float efx = __int_as_float(rec.y), efy = __int_as_float(rec.z);
      h2x4 up = *(const h2x4*)(subuf16 + (long)sid*8); // 16B fp16 su gather
      float2 u0 = __half22float2(up.a), u1 = __half22float2(up.b);
      float2 u2 = __half22float2(up.c), u3 = __half22float2(up.d);
      float suv[8] = {u0.x,u0.y,u1.x,u1.y,u2.x,u2.y,u3.x,u3.y};
      #pragma unroll
      for (int hh = 0; hh < 8; ++hh) {
        float v = suv[hh] + svn[hh] + efx*c0v[hh] + efy*c1v[hh] + cbv[hh];
        sc[hh] = (v > 0.f) ? v : 0.2f*v;   // leaky_relu 0.2
      }
    } else {
      #pragma unroll
      for (int hh = 0; hh < 8; ++hh) sc[hh] = -INFINITY;
    }
    // group max (xor masks <16 stay within the 16-lane group)
    float cm[8];
    #pragma unroll
    for (int hh = 0; hh < 8; ++hh) cm[hh] = sc[hh];
    #pragma unroll
    for (int sft = 8; sft >= 1; sft >>= 1) {
      #pragma unroll
      for (int hh = 0; hh < 8; ++hh)
        cm[hh] = fmaxf(cm[hh], __shfl_xor(cm[hh], sft, 64));
    }
    // online softmax update
    float f[8], pv[8];
    #pragma unroll
    for (int hh = 0; hh < 8; ++hh) {
      float nm = fmaxf(m8[hh], cm[hh]);
      f[hh] = __expf(m8[hh] - nm);
      pv[hh] = __expf(sc[hh] - nm);
      m8[hh] = nm;
    }
    if (sub < cnt) {
      // XOR-swizzled column: write 4-way, read conflict-free
      float4* pp = (float4*)&pbuf[wid][sub][g ^ (sub & 3)][0];
      pp[0] = make_float4(pv[0], pv[1], pv[2], pv[3]);
      pp[1] = make_float4(pv[4], pv[5], pv[6], pv[7]);
      sbuf[wid][sub][g ^ (sub & 3)] = sid;
    }
    // group denominator
    float q[8];
    #pragma unroll
    for (int hh = 0; hh < 8; ++hh) q[hh] = pv[hh];
    #pragma unroll
    for (int sft = 8; sft >= 1; sft >>= 1) {
      #pragma unroll
      for (int hh = 0; hh < 8; ++hh)
        q[hh] += __shfl_xor(q[hh], sft, 64);
    }
    #pragma unroll
    for (int hh = 0; hh < 8; ++hh) den8[hh] = den8[hh]*f[hh] + q[hh];
    // rescale msg: dims sub*4+i use head hb+i
    {
      float f0 = (sub & 1) ? f[4] : f[0];
      float f1 = (sub & 1) ? f[5] : f[1];
      float f2 = (sub & 1) ? f[6] : f[2];
      float f3 = (sub & 1) ? f[7] : f[3];
      msg.x *= f0; msg.y *= f1; msg.z *= f2; msg.w *= f3;
    }
    // wave-private LDS: waitcnt sufficient (no cross-wave sharing)
    asm volatile("s_waitcnt lgkmcnt(0)" ::: "memory");

    // message accumulation: lane owns dims sub*4..+3 (fp16 h gather, 8B/lane)
    #pragma unroll 4
    for (int e2 = 0; e2 < cnt; ++e2) {
      const int gs = g ^ (e2 & 3);
      int sidu = sbuf[wid][e2][gs];
      float4 p = *(const float4*)&pbuf[wid][e2][gs][hb];
      h2x2 hv = *(const h2x2*)(hbuf16 + (long)sidu*DIM + sub*4);
      float2 h01 = __half22float2(hv.a), h23 = __half22float2(hv.b);
      msg.x += h01.x*p.x; msg.y += h01.y*p.y; msg.z += h23.x*p.z; msg.w += h23.y*p.w;
    }
  }
  float d0 = (sub & 1) ? den8[4] : den8[0];
  float d1 = (sub & 1) ? den8[5] : den8[1];
  float d2 = (sub & 1) ? den8[6] : den8[2];
  float d3 = (sub & 1) ? den8[7] : den8[3];
  if (valid) {
    float4 o;
    o.x = msg.x / fmaxf(d0, 1e-12f);
    o.y = msg.y / fmaxf(d1, 1e-12f);
    o.z = msg.z / fmaxf(d2, 1e-12f);
    o.w = msg.w / fmaxf(d3, 1e-12f);
    *(float4*)(agg + n*DIM + sub*4) = o;
  }
}

// ---------------- FFN split: activations via SGPR scalar loads ----------------
// 16 nodes per wave: halves per-node weight re-read traffic vs 8.
__global__ __launch_bounds__(256) void ffn1_kernel(
    const float* __restrict__ agg,
    const float* __restrict__ w1, const float* __restrict__ b1,
    float* __restrict__ g, int n_nodes)
{
  const int wid  = __builtin_amdgcn_readfirstlane(threadIdx.x >> 6);  // wave-uniform
  const int lane = threadIdx.x & 63;
  const long nbase = (long)blockIdx.x * 64 + wid * 16;

  const float* xrow[16];
  #pragma unroll
  for (int m = 0; m < 16; ++m) {
    long n = nbase + m; if (n >= n_nodes) n = n_nodes - 1;
    xrow[m] = agg + n*DIM;            // uniform pointer -> scalar loads
  }
  float4 bb = *(const float4*)(b1 + lane*4);
  float h[16][4];
  #pragma unroll
  for (int m = 0; m < 16; ++m) { h[m][0]=bb.x; h[m][1]=bb.y; h[m][2]=bb.z; h[m][3]=bb.w; }

  #pragma unroll 4
  for (int k = 0; k < 64; ++k) {
    float4 w = *(const float4*)(w1 + k*HIDDEN + lane*4);   // coalesced 1KB
    #pragma unroll
    for (int m = 0; m < 16; ++m) {
      float xk = xrow[m][k];                               // SGPR operand
      h[m][0] += xk*w.x; h[m][1] += xk*w.y; h[m][2] += xk*w.z; h[m][3] += xk*w.w;
    }
  }
  #pragma unroll
  for (int m = 0; m < 16; ++m) {
    long n = nbase + m;
    if (n >= n_nodes) continue;
    float4 o;
    o.x = 0.5f*h[m][0]*(1.0f + erff(h[m][0]*0.70710678118654752f));
    o.y = 0.5f*h[m][1]*(1.0f + erff(h[m][1]*0.70710678118654752f));
    o.z = 0.5f*h[m][2]*(1.0f + erff(h[m][2]*0.70710678118654752f));
    o.w = 0.5f*h[m][3]*(1.0f + erff(h[m][3]*0.70710678118654752f));
    *(float4*)(g + n*HIDDEN + lane*4) = o;                 // coalesced 1KB
  }
}

__global__ __launch_bounds__(256) void ffn2_kernel(
    const float* __restrict__ g,
    const float* __restrict__ w2, const float* __restrict__ b2,
    float* __restrict__ out, int n_nodes)
{
  const int wid  = __builtin_amdgcn_readfirstlane(threadIdx.x >> 6);  // wave-uniform
  const int lane = threadIdx.x & 63;
  const long nbase = (long)blockIdx.x * 64 + wid * 16;

  const float* grow[16];
  #pragma unroll
  for (int m = 0; m < 16; ++m) {
    long n = nbase + m; if (n >= n_nodes) n = n_nodes - 1;
    grow[m] = g + n*HIDDEN;           // uniform pointer -> scalar loads
  }
  const float b2v = b2[lane];
  float acc[16];
  #pragma unroll
  for (int m = 0; m < 16; ++m) acc[m] = b2v;

  #pragma unroll 4
  for (int j = 0; j < HIDDEN; ++j) {
    float wv = w2[j*DIM + lane];      // coalesced 256B
    #pragma unroll
    for (int m = 0; m < 16; ++m)
      acc[m] += grow[m][j] * wv;      // SGPR x VGPR FMA
  }
  #pragma unroll
  for (int m = 0; m < 16; ++m) {
    long n = nbase + m;
    if (n < n_nodes) out[n*DIM + lane] = acc[m];
  }
}

// ---------------- launch ----------------
extern "C" void kernel_launch(void* const* d_in, const int* in_sizes, int n_in,
                              void* d_out, int out_size, void* d_ws, size_t ws_size,
                              hipStream_t stream)
{
  const float* x         = (const float*)d_in[0];
  const float* edge_feat = (const float*)d_in[1];
  const float* w_in      = (const float*)d_in[2];
  const float* b_in      = (const float*)d_in[3];
  const float* w_edge    = (const float*)d_in[4];
  const float* b_edge    = (const float*)d_in[5];
  const float* w_att_u   = (const float*)d_in[6];
  const float* b_att_u   = (const float*)d_in[7];
  const float* w_att_v   = (const float*)d_in[8];
  const float* w_att_e   = (const float*)d_in[9];
  const float* b_att_e   = (const float*)d_in[10];
  const float* w_ff1     = (const float*)d_in[11];
  const float* b_ff1     = (const float*)d_in[12];
  const float* w_ff2     = (const float*)d_in[13];
  const float* b_ff2     = (const float*)d_in[14];
  const int*   src       = (const int*)d_in[15];
  const int*   dst       = (const int*)d_in[16];
  float* out = (float*)d_out;

  const int n_nodes = in_sizes[0] / DIM;
  const int n_edges = in_sizes[15];

  char* p = (char*)d_ws;
  auto alloc_b = [&](size_t bytes) { char* r = p; p += ((bytes + 255) & ~(size_t)255); return r; };
  float*  Waug    = (float*)alloc_b(64*80*4);
  float*  baug    = (float*)alloc_b(80*4);
  float*  wcc     = (float*)alloc_b(16*4);
  float*  bcc     = (float*)alloc_b(8*4);
  float*  aggb    = (float*)alloc_b((size_t)n_nodes*DIM*4);   // live until ffn1
  __half* hbuf16  = (__half*)alloc_b((size_t)n_nodes*DIM*2);  // dead after attn
  __half* subuf16 = (__half*)alloc_b((size_t)n_nodes*8*2);    // dead after attn
  float*  svbuf   = (float*)alloc_b((size_t)n_nodes*8*4);     // dead after attn
  int*    deg     = (int*)alloc_b((size_t)n_nodes*4);         // dead after attn
  int*    pos     = (int*)alloc_b((size_t)n_nodes*4);         // dead after scatter
  int*    counter = (int*)alloc_b(256);
  int*    offb    = (int*)alloc_b((size_t)n_nodes*4);         // dead after attn
  int4*   recs    = (int4*)alloc_b((size_t)n_edges*16);       // dead after attn
  // g[N,256] fp32 aliases the dead-after-attn region starting at hbuf16
  float*  gbuf    = (float*)hbuf16;

  // zero deg, pos, counter in one shot (contiguous in the layout)
  hipMemsetAsync(deg, 0, (size_t)((char*)offb - (char*)deg), stream);

  hipLaunchKernelGGL(prep_kernel, dim3(1), dim3(256), 0, stream,
      w_in, b_in, w_edge, b_edge, w_att_u, b_att_u, w_att_v, w_att_e, b_att_e,
      Waug, baug, wcc, bcc);

  hipLaunchKernelGGL(node_gemm_kernel, dim3((n_nodes+31)/32), dim3(256), 0, stream,
      x, Waug, baug, hbuf16, subuf16, svbuf, n_nodes);

  hipLaunchKernelGGL(hist_kernel, dim3((n_edges+255)/256), dim3(256), 0, stream,
      dst, deg, n_edges);
  hipLaunchKernelGGL(alloc_kernel, dim3((n_nodes+255)/256), dim3(256), 0, stream,
      deg, offb, counter, n_nodes);
  hipLaunchKernelGGL(scatter_kernel, dim3((n_edges+255)/256), dim3(256), 0, stream,
      dst, src, edge_feat, offb, pos, recs, n_edges);

  hipLaunchKernelGGL(attn_kernel, dim3((n_nodes+15)/16), dim3(256), 0, stream,
      recs, offb, deg, hbuf16, subuf16, svbuf, wcc, bcc, aggb, n_nodes);

  hipLaunchKernelGGL(ffn1_kernel, dim3((n_nodes+63)/64), dim3(256), 0, stream,
      aggb, w_ff1, b_ff1, gbuf, n_nodes);

  hipLaunchKernelGGL(ffn2_kernel, dim3((n_nodes+63)/64), dim3(256), 0, stream,
      gbuf, w_ff2, b_ff2, out, n_nodes);
}